// Round 8
// baseline (432.890 us; speedup 1.0000x reference)
//
#include <hip/hip_runtime.h>
#include <hip/hip_bf16.h>
#include <math.h>

#define N_NODES 40000
#define N_EDGES 640000
#define N_GRAPH 64
#define HEADS 4
#define CHAN 64
#define HC 256          // HEADS*CHAN
#define NHID 1024
#define NOUT 768
#define E_TOT (N_EDGES + N_NODES)
#define SCAN_NB ((N_NODES + 255) / 256)   // 157

typedef __attribute__((ext_vector_type(8))) short bf16x8;
typedef __attribute__((ext_vector_type(4))) float f32x4;
typedef __attribute__((ext_vector_type(2))) float f32x2;

__device__ inline float bflo(unsigned u) { return __uint_as_float(u << 16); }
__device__ inline float bfhi(unsigned u) { return __uint_as_float(u & 0xffff0000u); }

__device__ inline f32x2 unpk2(unsigned u) {
    return (f32x2){__uint_as_float(u << 16), __uint_as_float(u & 0xffff0000u)};
}
// packed fp32 fma: a += w2 * h2  (one VALU instr, 2 lanes-worth of fma)
__device__ inline void pkfma(f32x2& a, f32x2 w2, f32x2 h2) {
    asm("v_pk_fma_f32 %0, %1, %2, %0" : "+v"(a) : "v"(w2), "v"(h2));
}

__device__ inline unsigned bfbits(float f) {
    __hip_bfloat16 b = __float2bfloat16(f);
    return (unsigned)*reinterpret_cast<unsigned short*>(&b);
}
__device__ inline unsigned pk2bf(float lo, float hi) {
    return bfbits(lo) | (bfbits(hi) << 16);
}

// ---------------- dtype conversion ----------------

__global__ void cast_x_kernel(const float* __restrict__ x, __hip_bfloat16* __restrict__ xb) {
    int i = blockIdx.x * blockDim.x + threadIdx.x;      // handles 4 elems
    float4 v = *reinterpret_cast<const float4*>(&x[(size_t)i * 4]);
    __hip_bfloat16 o[4] = {__float2bfloat16(v.x), __float2bfloat16(v.y),
                           __float2bfloat16(v.z), __float2bfloat16(v.w)};
    *reinterpret_cast<ushort4*>(&xb[(size_t)i * 4]) = *reinterpret_cast<ushort4*>(o);
}

// Wt[n][k] = bf16(W[k][n]) for all 3 layer weights in one launch
__global__ void conv_wt3_kernel(const float* __restrict__ W1, const float* __restrict__ W2,
                                const float* __restrict__ W3, __hip_bfloat16* __restrict__ T1,
                                __hip_bfloat16* __restrict__ T2, __hip_bfloat16* __restrict__ T3) {
    const float* W = (blockIdx.y == 0) ? W1 : (blockIdx.y == 1) ? W2 : W3;
    __hip_bfloat16* T = (blockIdx.y == 0) ? T1 : (blockIdx.y == 1) ? T2 : T3;
    int k = blockIdx.x, n = threadIdx.x;
    T[(size_t)n * 256 + k] = __float2bfloat16(W[(size_t)k * 256 + n]);
}

// ---------------- CSR build ----------------

__global__ void count_deg_kernel(const int* __restrict__ ei, int* __restrict__ deg) {
    int i = blockIdx.x * blockDim.x + threadIdx.x;
    if (i >= E_TOT) return;
    int dst = (i < N_EDGES) ? ei[N_EDGES + i] : (i - N_EDGES);
    atomicAdd(&deg[dst], 1);
}

__global__ __launch_bounds__(256)
void scan_p1_kernel(const int* __restrict__ deg, int* __restrict__ bsum) {
    const int b = blockIdx.x, t = threadIdx.x;
    const int i = b * 256 + t;
    int v = (i < N_NODES) ? deg[i] : 0;
    #pragma unroll
    for (int off = 1; off < 64; off <<= 1) v += __shfl_xor(v, off, 64);
    __shared__ int ws[4];
    if ((t & 63) == 0) ws[t >> 6] = v;
    __syncthreads();
    if (t == 0) bsum[b] = ws[0] + ws[1] + ws[2] + ws[3];
}

__global__ __launch_bounds__(256)
void scan_p2_kernel(int* __restrict__ bsum) {     // single block; SCAN_NB <= 256
    __shared__ int s[256];
    const int t = threadIdx.x;
    int v = (t < SCAN_NB) ? bsum[t] : 0;
    s[t] = v;
    __syncthreads();
    #pragma unroll
    for (int off = 1; off < 256; off <<= 1) {
        int x = (t >= off) ? s[t - off] : 0;
        __syncthreads();
        s[t] += x;
        __syncthreads();
    }
    if (t < SCAN_NB) bsum[t] = s[t] - v;          // exclusive block offset
}

__global__ __launch_bounds__(256)
void scan_p3_kernel(const int* __restrict__ deg, const int* __restrict__ bsum,
                    int* __restrict__ rowptr) {
    __shared__ int s[256];
    const int b = blockIdx.x, t = threadIdx.x;
    const int i = b * 256 + t;
    int v = (i < N_NODES) ? deg[i] : 0;
    s[t] = v;
    __syncthreads();
    #pragma unroll
    for (int off = 1; off < 256; off <<= 1) {
        int x = (t >= off) ? s[t - off] : 0;
        __syncthreads();
        s[t] += x;
        __syncthreads();
    }
    if (i < N_NODES) rowptr[i] = bsum[b] + s[t] - v;
    if (i == 0) rowptr[N_NODES] = E_TOT;          // total is static
}

__global__ void fill_csr_kernel(const int* __restrict__ ei, const int* __restrict__ rowptr,
                                int* __restrict__ cursor, int* __restrict__ csr_src) {
    int i = blockIdx.x * blockDim.x + threadIdx.x;
    if (i >= E_TOT) return;
    int src, dst;
    if (i < N_EDGES) { src = ei[i]; dst = ei[N_EDGES + i]; }
    else             { src = dst = i - N_EDGES; }
    int pos = atomicAdd(&cursor[dst], 1);
    csr_src[rowptr[dst] + pos] = src;
}

// ---------------- bf16 MFMA GEMM, tile 64x256, reg-staged pipeline ----------------
// grid = 625 (= 40000/64 exactly, no tail). 4 waves; wave wc owns cols [wc*64, wc*64+64)
// == head wc. K-step 32, 8 iters; next tile's global loads issued before MFMA (T14).
// Epilogue: acc -> per-wave LDS f32 strip -> vectorized bf16 stores + fused alpha dot.

__global__ __launch_bounds__(256)
void gemm_mfma_kernel(const __hip_bfloat16* __restrict__ A, const __hip_bfloat16* __restrict__ Wt,
                      __hip_bfloat16* __restrict__ C,
                      const float* __restrict__ a_s, const float* __restrict__ a_d,
                      float* __restrict__ asrc, float* __restrict__ adst) {
    __shared__ __align__(16) union {
        struct { ushort A[64][40]; ushort B[256][40]; } t;   // pad 32->40: ~2-way banks (free)
        float strip[4][16][68];                              // per-wave epilogue repack
    } lds;

    const int tid = threadIdx.x;
    const int lane = tid & 63;
    const int l15 = lane & 15;
    const int lq  = lane >> 4;
    const int wc  = tid >> 6;               // wave -> 64-col strip == head
    const int row0 = blockIdx.x * 64;

    const char* Ab = (const char*)A;
    const char* Wb = (const char*)Wt;

    // staging decomposition: 16B unit per thread for A (64x32), 4 units for B (256x32)
    const int ar = tid >> 2;                // 0..63  (A row / B col base)
    const int aq = tid & 3;                 // 16B quarter within 64B k-row
    const size_t a_goff = (size_t)(row0 + ar) * 512 + aq * 16;

    f32x4 acc[4][4];
    #pragma unroll
    for (int m = 0; m < 4; m++)
        #pragma unroll
        for (int n = 0; n < 4; n++)
            acc[m][n] = (f32x4){0.f, 0.f, 0.f, 0.f};

    uint4 ra, rb0, rb1, rb2, rb3;
    // prologue: stage tile 0
    ra  = *reinterpret_cast<const uint4*>(Ab + a_goff);
    rb0 = *reinterpret_cast<const uint4*>(Wb + (size_t)(ar      ) * 512 + aq * 16);
    rb1 = *reinterpret_cast<const uint4*>(Wb + (size_t)(ar +  64) * 512 + aq * 16);
    rb2 = *reinterpret_cast<const uint4*>(Wb + (size_t)(ar + 128) * 512 + aq * 16);
    rb3 = *reinterpret_cast<const uint4*>(Wb + (size_t)(ar + 192) * 512 + aq * 16);
    *reinterpret_cast<uint4*>(&lds.t.A[ar][aq * 8]) = ra;
    *reinterpret_cast<uint4*>(&lds.t.B[ar][aq * 8]) = rb0;
    *reinterpret_cast<uint4*>(&lds.t.B[ar + 64][aq * 8]) = rb1;
    *reinterpret_cast<uint4*>(&lds.t.B[ar + 128][aq * 8]) = rb2;
    *reinterpret_cast<uint4*>(&lds.t.B[ar + 192][aq * 8]) = rb3;
    __syncthreads();

    for (int kt = 0; kt < 8; ++kt) {
        if (kt < 7) {   // issue next tile's loads early; they fly under the MFMAs
            const size_t ko = (size_t)(kt + 1) * 64;
            ra  = *reinterpret_cast<const uint4*>(Ab + a_goff + ko);
            rb0 = *reinterpret_cast<const uint4*>(Wb + (size_t)(ar      ) * 512 + aq * 16 + ko);
            rb1 = *reinterpret_cast<const uint4*>(Wb + (size_t)(ar +  64) * 512 + aq * 16 + ko);
            rb2 = *reinterpret_cast<const uint4*>(Wb + (size_t)(ar + 128) * 512 + aq * 16 + ko);
            rb3 = *reinterpret_cast<const uint4*>(Wb + (size_t)(ar + 192) * 512 + aq * 16 + ko);
        }
        bf16x8 af[4], bfr[4];
        #pragma unroll
        for (int m = 0; m < 4; m++)
            af[m] = *reinterpret_cast<const bf16x8*>(&lds.t.A[m * 16 + l15][lq * 8]);
        #pragma unroll
        for (int n = 0; n < 4; n++)
            bfr[n] = *reinterpret_cast<const bf16x8*>(&lds.t.B[wc * 64 + n * 16 + l15][lq * 8]);
        #pragma unroll
        for (int m = 0; m < 4; m++)
            #pragma unroll
            for (int n = 0; n < 4; n++)
                acc[m][n] = __builtin_amdgcn_mfma_f32_16x16x32_bf16(af[m], bfr[n], acc[m][n], 0, 0, 0);
        __syncthreads();
        if (kt < 7) {
            *reinterpret_cast<uint4*>(&lds.t.A[ar][aq * 8]) = ra;
            *reinterpret_cast<uint4*>(&lds.t.B[ar][aq * 8]) = rb0;
            *reinterpret_cast<uint4*>(&lds.t.B[ar + 64][aq * 8]) = rb1;
            *reinterpret_cast<uint4*>(&lds.t.B[ar + 128][aq * 8]) = rb2;
            *reinterpret_cast<uint4*>(&lds.t.B[ar + 192][aq * 8]) = rb3;
            __syncthreads();
        }
    }

    // epilogue: per m-strip, repack acc through per-wave LDS, fused alpha dot + vector stores.
    // (kt=7 barrier above already fenced all LDS reads; strips are wave-private.)
    const int head = wc;
    const int r  = lane >> 2;               // output row within strip
    const int cq = lane & 3;                // 16-col quarter within wave's 64 cols
    #pragma unroll
    for (int m = 0; m < 4; m++) {
        #pragma unroll
        for (int n = 0; n < 4; n++)
            #pragma unroll
            for (int reg = 0; reg < 4; reg++)
                lds.strip[wc][lq * 4 + reg][n * 16 + l15] = acc[m][n][reg];
        f32x4 c0 = *reinterpret_cast<const f32x4*>(&lds.strip[wc][r][cq * 16]);
        f32x4 c1 = *reinterpret_cast<const f32x4*>(&lds.strip[wc][r][cq * 16 + 4]);
        f32x4 c2 = *reinterpret_cast<const f32x4*>(&lds.strip[wc][r][cq * 16 + 8]);
        f32x4 c3 = *reinterpret_cast<const f32x4*>(&lds.strip[wc][r][cq * 16 + 12]);
        // alpha partial dot over this lane's 16 cols
        float ps = 0.f, pd = 0.f;
        #pragma unroll
        for (int k4 = 0; k4 < 4; k4++) {
            f32x4 cv = (k4 == 0) ? c0 : (k4 == 1) ? c1 : (k4 == 2) ? c2 : c3;
            #pragma unroll
            for (int j = 0; j < 4; j++) {
                float wsv = a_s[head * 64 + cq * 16 + k4 * 4 + j];
                float wdv = a_d[head * 64 + cq * 16 + k4 * 4 + j];
                ps = fmaf(cv[j], wsv, ps);
                pd = fmaf(cv[j], wdv, pd);
            }
        }
        ps += __shfl_xor(ps, 1, 4); ps += __shfl_xor(ps, 2, 4);
        pd += __shfl_xor(pd, 1, 4); pd += __shfl_xor(pd, 2, 4);
        const int row = row0 + m * 16 + r;
        if (cq == 0) {
            asrc[row * 4 + head] = ps;
            adst[row * 4 + head] = pd;
        }
        uint4 o0 = make_uint4(pk2bf(c0[0], c0[1]), pk2bf(c0[2], c0[3]),
                              pk2bf(c1[0], c1[1]), pk2bf(c1[2], c1[3]));
        uint4 o1 = make_uint4(pk2bf(c2[0], c2[1]), pk2bf(c2[2], c2[3]),
                              pk2bf(c3[0], c3[1]), pk2bf(c3[2], c3[3]));
        __hip_bfloat16* Cp = C + (size_t)row * 256 + wc * 64 + cq * 16;
        *reinterpret_cast<uint4*>(Cp) = o0;
        *reinterpret_cast<uint4*>(Cp + 8) = o1;
    }
}

// ---------------- fused edge-softmax + aggregation (max-free, wave-per-head) ----------------

#define ACHUNK 256

__global__ __launch_bounds__(256)
void gat_fused_agg(const __hip_bfloat16* __restrict__ h, const float* __restrict__ asrc,
                   const float* __restrict__ adst, const int* __restrict__ rowptr,
                   const int* __restrict__ csr_src, const float* __restrict__ bias,
                   __hip_bfloat16* __restrict__ out, int do_relu) {
    __shared__ int   s_src[ACHUNK];
    __shared__ float s_w[ACHUNK][5];    // pad 4->5: conflict-free phase-0 writes
    __shared__ float s_acc[8][HC];
    __shared__ float s_sum[4];

    const int n = blockIdx.x;
    const int t = threadIdx.x;
    const int lane = t & 63;
    const int wid = t >> 6;         // wave id == head in phase 0
    const int grp = t >> 5;         // phase-1 group (edge parity)
    const int gl  = t & 31;         // lane in group; channels gl*8..gl*8+7
    const int h3  = gl >> 3;        // head owning those channels
    const int start = rowptr[n];
    const int deg = rowptr[n + 1] - start;
    const float ad = adst[n * 4 + wid];

    float ssum = 0.f;
    f32x2 ap0 = {0.f, 0.f}, ap1 = {0.f, 0.f}, ap2 = {0.f, 0.f}, ap3 = {0.f, 0.f};

    for (int c0 = 0; c0 < deg; c0 += ACHUNK) {
        const int cn = min(ACHUNK, deg - c0);
        if (c0) __syncthreads();
        for (int e = lane; e < cn; e += 64) {
            int src = csr_src[start + c0 + e];
            if (wid == 0) s_src[e] = src;
            float sc = asrc[src * 4 + wid] + ad;
            sc = (sc >= 0.f) ? sc : 0.2f * sc;   // leaky relu 0.2
            float w = __expf(sc);
            s_w[e][wid] = w;
            ssum += w;
        }
        __syncthreads();
        #pragma unroll 2
        for (int e = grp; e < cn; e += 8) {
            float w = s_w[e][h3];
            f32x2 w2 = {w, w};
            uint4 v = *reinterpret_cast<const uint4*>(&h[(size_t)s_src[e] * HC + gl * 8]);
            pkfma(ap0, w2, unpk2(v.x));
            pkfma(ap1, w2, unpk2(v.y));
            pkfma(ap2, w2, unpk2(v.z));
            pkfma(ap3, w2, unpk2(v.w));
        }
    }
    #pragma unroll
    for (int off = 1; off < 64; off <<= 1) ssum += __shfl_xor(ssum, off, 64);
    if (lane == 0) s_sum[wid] = ssum;
    s_acc[grp][gl * 8 + 0] = ap0.x; s_acc[grp][gl * 8 + 1] = ap0.y;
    s_acc[grp][gl * 8 + 2] = ap1.x; s_acc[grp][gl * 8 + 3] = ap1.y;
    s_acc[grp][gl * 8 + 4] = ap2.x; s_acc[grp][gl * 8 + 5] = ap2.y;
    s_acc[grp][gl * 8 + 6] = ap3.x; s_acc[grp][gl * 8 + 7] = ap3.y;
    __syncthreads();
    float tot = 0.f;
    #pragma unroll
    for (int g = 0; g < 8; g++) tot += s_acc[g][t];
    float r = tot / s_sum[t >> 6] + bias[t];
    if (do_relu) r = fmaxf(r, 0.f);
    out[(size_t)n * HC + t] = __float2bfloat16(r);
}

// ---------------- pooling (batch sorted): one block per graph, no atomics ----------------

__global__ void graph_bounds_kernel(const int* __restrict__ batch, int* __restrict__ cnt) {
    int g = threadIdx.x;
    if (g >= N_GRAPH) return;
    int lo = 0, hi = N_NODES;
    while (lo < hi) { int mid = (lo + hi) >> 1; if (batch[mid] < g) lo = mid + 1; else hi = mid; }
    int start = lo;
    lo = 0; hi = N_NODES;
    while (lo < hi) { int mid = (lo + hi) >> 1; if (batch[mid] < g + 1) lo = mid + 1; else hi = mid; }
    cnt[g] = lo - start;
}

__global__ __launch_bounds__(256)
void pool_kernel(const __hip_bfloat16* __restrict__ h, const int* __restrict__ batch,
                 float* __restrict__ pooled) {
    __shared__ float s_acc[8][HC];
    const int g = blockIdx.x;
    const int t = threadIdx.x;
    const int grp = t >> 5;
    const int gl  = t & 31;
    int lo = 0, hi = N_NODES;
    while (lo < hi) { int mid = (lo + hi) >> 1; if (batch[mid] < g) lo = mid + 1; else hi = mid; }
    const int start = lo;
    lo = 0; hi = N_NODES;
    while (lo < hi) { int mid = (lo + hi) >> 1; if (batch[mid] < g + 1) lo = mid + 1; else hi = mid; }
    const int end = lo;

    float acc[8] = {0.f, 0.f, 0.f, 0.f, 0.f, 0.f, 0.f, 0.f};
    for (int n = start + grp; n < end; n += 8) {
        uint4 v = *reinterpret_cast<const uint4*>(&h[(size_t)n * HC + gl * 8]);
        acc[0] += bflo(v.x); acc[1] += bfhi(v.x);
        acc[2] += bflo(v.y); acc[3] += bfhi(v.y);
        acc[4] += bflo(v.z); acc[5] += bfhi(v.z);
        acc[6] += bflo(v.w); acc[7] += bfhi(v.w);
    }
    #pragma unroll
    for (int j = 0; j < 8; j++) s_acc[grp][gl * 8 + j] = acc[j];
    __syncthreads();
    float tot = 0.f;
    #pragma unroll
    for (int q = 0; q < 8; q++) tot += s_acc[q][t];
    pooled[g * HC + t] = tot;
}

// ---------------- MLP head ----------------

__global__ __launch_bounds__(1024)
void mlp1_kernel(const float* __restrict__ pooled, const int* __restrict__ cnt,
                 const float* __restrict__ W, const float* __restrict__ b,
                 float* __restrict__ hidden) {
    __shared__ float row[256];
    const int g = blockIdx.x, t = threadIdx.x;
    if (t < 256) {
        float c = (float)max(cnt[g], 1);
        row[t] = pooled[g * 256 + t] / c;
    }
    __syncthreads();
    float acc = b[t];
    for (int k = 0; k < 256; k++) acc = fmaf(row[k], W[(size_t)k * NHID + t], acc);
    hidden[g * NHID + t] = fmaxf(acc, 0.f);
}

__global__ __launch_bounds__(768)
void mlp2_kernel(const float* __restrict__ hidden, const float* __restrict__ W,
                 const float* __restrict__ b, float* __restrict__ out) {
    __shared__ float row[NHID];
    const int g = blockIdx.x, t = threadIdx.x;
    row[t] = hidden[g * NHID + t];
    if (t < NHID - NOUT) row[NOUT + t] = hidden[g * NHID + NOUT + t];
    __syncthreads();
    float acc = b[t];
    for (int k = 0; k < NHID; k++) acc = fmaf(row[k], W[(size_t)k * NOUT + t], acc);
    out[g * NOUT + t] = acc;
}

// ---------------- launch ----------------

extern "C" void kernel_launch(void* const* d_in, const int* in_sizes, int n_in,
                              void* d_out, int out_size, void* d_ws, size_t ws_size,
                              hipStream_t stream) {
    const float* x  = (const float*)d_in[0];
    const int* ei   = (const int*)d_in[1];
    const int* batch = (const int*)d_in[2];
    const float* W1 = (const float*)d_in[3];
    const float* as1 = (const float*)d_in[4];
    const float* ad1 = (const float*)d_in[5];
    const float* b1 = (const float*)d_in[6];
    const float* W2 = (const float*)d_in[7];
    const float* as2 = (const float*)d_in[8];
    const float* ad2 = (const float*)d_in[9];
    const float* b2 = (const float*)d_in[10];
    const float* W3 = (const float*)d_in[11];
    const float* as3 = (const float*)d_in[12];
    const float* ad3 = (const float*)d_in[13];
    const float* b3 = (const float*)d_in[14];
    const float* Wm1 = (const float*)d_in[15];
    const float* bm1 = (const float*)d_in[16];
    const float* Wm2 = (const float*)d_in[17];
    const float* bm2 = (const float*)d_in[18];
    float* out = (float*)d_out;

    char* base = (char*)d_ws;
    size_t off = 0;
    auto alloc = [&](size_t bytes) { char* p = base + off; off = (off + bytes + 255) & ~(size_t)255; return p; };
    __hip_bfloat16* x_bf = (__hip_bfloat16*)alloc((size_t)N_NODES * 256 * 2);
    __hip_bfloat16* hA   = (__hip_bfloat16*)alloc((size_t)N_NODES * 256 * 2);
    __hip_bfloat16* hB   = (__hip_bfloat16*)alloc((size_t)N_NODES * 256 * 2);
    __hip_bfloat16* Wt1  = (__hip_bfloat16*)alloc((size_t)256 * 256 * 2);
    __hip_bfloat16* Wt2  = (__hip_bfloat16*)alloc((size_t)256 * 256 * 2);
    __hip_bfloat16* Wt3  = (__hip_bfloat16*)alloc((size_t)256 * 256 * 2);
    float* asrc   = (float*)alloc((size_t)N_NODES * 4 * 4);
    float* adst   = (float*)alloc((size_t)N_NODES * 4 * 4);
    int*   deg    = (int*)alloc((size_t)N_NODES * 4);
    int*   cursor = (int*)alloc((size_t)N_NODES * 4);
    int*   rowptr = (int*)alloc((size_t)(N_NODES + 1) * 4);
    int*   bsum   = (int*)alloc((size_t)SCAN_NB * 4);
    int*   csrsrc = (int*)alloc((size_t)E_TOT * 4);
    float* pooled = (float*)alloc((size_t)N_GRAPH * 256 * 4);
    int*   cnt    = (int*)alloc((size_t)N_GRAPH * 4);
    float* hidden = (float*)alloc((size_t)N_GRAPH * NHID * 4);
    (void)ws_size; (void)n_in; (void)in_sizes; (void)out_size;

    hipMemsetAsync(deg, 0, (size_t)N_NODES * 4, stream);
    hipMemsetAsync(cursor, 0, (size_t)N_NODES * 4, stream);

    // dtype prep
    cast_x_kernel<<<(N_NODES * 256 / 4 + 255) / 256, 256, 0, stream>>>(x, x_bf);
    conv_wt3_kernel<<<dim3(256, 3), 256, 0, stream>>>(W1, W2, W3, Wt1, Wt2, Wt3);

    // CSR (multi-block scan)
    const int eb = (E_TOT + 255) / 256;
    count_deg_kernel<<<eb, 256, 0, stream>>>(ei, deg);
    scan_p1_kernel<<<SCAN_NB, 256, 0, stream>>>(deg, bsum);
    scan_p2_kernel<<<1, 256, 0, stream>>>(bsum);
    scan_p3_kernel<<<SCAN_NB, 256, 0, stream>>>(deg, bsum, rowptr);
    fill_csr_kernel<<<eb, 256, 0, stream>>>(ei, rowptr, cursor, csrsrc);

    const int ggrid = N_NODES / 64;   // 625, exact

    // layer 1
    gemm_mfma_kernel<<<ggrid, 256, 0, stream>>>(x_bf, Wt1, hA, as1, ad1, asrc, adst);
    gat_fused_agg<<<N_NODES, 256, 0, stream>>>(hA, asrc, adst, rowptr, csrsrc, b1, hB, 1);
    // layer 2
    gemm_mfma_kernel<<<ggrid, 256, 0, stream>>>(hB, Wt2, hA, as2, ad2, asrc, adst);
    gat_fused_agg<<<N_NODES, 256, 0, stream>>>(hA, asrc, adst, rowptr, csrsrc, b2, hB, 1);
    // layer 3
    gemm_mfma_kernel<<<ggrid, 256, 0, stream>>>(hB, Wt3, hA, as3, ad3, asrc, adst);
    gat_fused_agg<<<N_NODES, 256, 0, stream>>>(hA, asrc, adst, rowptr, csrsrc, b3, hB, 0);

    // pool + MLP
    graph_bounds_kernel<<<1, 64, 0, stream>>>(batch, cnt);
    pool_kernel<<<N_GRAPH, 256, 0, stream>>>(hB, batch, pooled);
    mlp1_kernel<<<N_GRAPH, 1024, 0, stream>>>(pooled, cnt, Wm1, bm1, hidden);
    mlp2_kernel<<<N_GRAPH, NOUT, 0, stream>>>(hidden, Wm2, bm2, out);
}

// Round 9
// 422.132 us; speedup vs baseline: 1.0255x; 1.0255x over previous
//
#include <hip/hip_runtime.h>
#include <hip/hip_bf16.h>
#include <math.h>

#define N_NODES 40000
#define N_EDGES 640000
#define N_GRAPH 64
#define HEADS 4
#define CHAN 64
#define HC 256          // HEADS*CHAN
#define NHID 1024
#define NOUT 768
#define E_TOT (N_EDGES + N_NODES)
#define SCAN_NB ((N_NODES + 255) / 256)   // 157

typedef __attribute__((ext_vector_type(8))) short bf16x8;
typedef __attribute__((ext_vector_type(4))) float f32x4;

__device__ inline float bflo(unsigned u) { return __uint_as_float(u << 16); }
__device__ inline float bfhi(unsigned u) { return __uint_as_float(u & 0xffff0000u); }

__device__ inline unsigned bfbits(float f) {
    __hip_bfloat16 b = __float2bfloat16(f);
    return (unsigned)*reinterpret_cast<unsigned short*>(&b);
}
__device__ inline unsigned pk2bf(float lo, float hi) {
    return bfbits(lo) | (bfbits(hi) << 16);
}

// ---------------- weight transpose (all 3 layers, one launch) ----------------

__global__ void conv_wt3_kernel(const float* __restrict__ W1, const float* __restrict__ W2,
                                const float* __restrict__ W3, __hip_bfloat16* __restrict__ T1,
                                __hip_bfloat16* __restrict__ T2, __hip_bfloat16* __restrict__ T3) {
    const float* W = (blockIdx.y == 0) ? W1 : (blockIdx.y == 1) ? W2 : W3;
    __hip_bfloat16* T = (blockIdx.y == 0) ? T1 : (blockIdx.y == 1) ? T2 : T3;
    int k = blockIdx.x, n = threadIdx.x;
    T[(size_t)n * 256 + k] = __float2bfloat16(W[(size_t)k * 256 + n]);
}

// ---------------- CSR build ----------------

__global__ void count_deg_kernel(const int* __restrict__ ei, int* __restrict__ deg) {
    int i = blockIdx.x * blockDim.x + threadIdx.x;
    if (i >= E_TOT) return;
    int dst = (i < N_EDGES) ? ei[N_EDGES + i] : (i - N_EDGES);
    atomicAdd(&deg[dst], 1);
}

__global__ __launch_bounds__(256)
void scan_p1_kernel(const int* __restrict__ deg, int* __restrict__ bsum) {
    const int b = blockIdx.x, t = threadIdx.x;
    const int i = b * 256 + t;
    int v = (i < N_NODES) ? deg[i] : 0;
    #pragma unroll
    for (int off = 1; off < 64; off <<= 1) v += __shfl_xor(v, off, 64);
    __shared__ int ws[4];
    if ((t & 63) == 0) ws[t >> 6] = v;
    __syncthreads();
    if (t == 0) bsum[b] = ws[0] + ws[1] + ws[2] + ws[3];
}

__global__ __launch_bounds__(256)
void scan_p2_kernel(int* __restrict__ bsum) {     // single block; SCAN_NB <= 256
    __shared__ int s[256];
    const int t = threadIdx.x;
    int v = (t < SCAN_NB) ? bsum[t] : 0;
    s[t] = v;
    __syncthreads();
    #pragma unroll
    for (int off = 1; off < 256; off <<= 1) {
        int x = (t >= off) ? s[t - off] : 0;
        __syncthreads();
        s[t] += x;
        __syncthreads();
    }
    if (t < SCAN_NB) bsum[t] = s[t] - v;          // exclusive block offset
}

__global__ __launch_bounds__(256)
void scan_p3_kernel(const int* __restrict__ deg, const int* __restrict__ bsum,
                    int* __restrict__ rowptr) {
    __shared__ int s[256];
    const int b = blockIdx.x, t = threadIdx.x;
    const int i = b * 256 + t;
    int v = (i < N_NODES) ? deg[i] : 0;
    s[t] = v;
    __syncthreads();
    #pragma unroll
    for (int off = 1; off < 256; off <<= 1) {
        int x = (t >= off) ? s[t - off] : 0;
        __syncthreads();
        s[t] += x;
        __syncthreads();
    }
    if (i < N_NODES) rowptr[i] = bsum[b] + s[t] - v;
    if (i == 0) rowptr[N_NODES] = E_TOT;          // total is static
}

__global__ void fill_csr_kernel(const int* __restrict__ ei, const int* __restrict__ rowptr,
                                int* __restrict__ cursor, int* __restrict__ csr_src) {
    int i = blockIdx.x * blockDim.x + threadIdx.x;
    if (i >= E_TOT) return;
    int src, dst;
    if (i < N_EDGES) { src = ei[i]; dst = ei[N_EDGES + i]; }
    else             { src = dst = i - N_EDGES; }
    int pos = atomicAdd(&cursor[dst], 1);
    csr_src[rowptr[dst] + pos] = src;
}

// ---------------- bf16 MFMA GEMM, tile 32x256, 1-barrier LDS double-buffer ----------------
// grid = 1250 (40000/32). 4 waves; wave wc owns cols [wc*64,+64) == head wc.
// K-step 32, 8 iters. Per iter: ds_read frags(cur) -> issue next-tile global loads
// -> MFMA -> ds_write(other buf) -> ONE barrier. CAST=1: A is f32, cast during staging.

template<int CAST>
__global__ __launch_bounds__(256)
void gemm_mfma_kernel(const void* __restrict__ Ain, const __hip_bfloat16* __restrict__ Wt,
                      __hip_bfloat16* __restrict__ C,
                      const float* __restrict__ a_s, const float* __restrict__ a_d,
                      float* __restrict__ asrc, float* __restrict__ adst) {
    __shared__ __align__(16) union {
        struct { ushort A0[32][32]; ushort B0[256][32]; ushort A1[32][32]; ushort B1[256][32]; } t;
        float strip[4][16][68];   // aliases A0+B0 (17.4KB <= 18KB); last K-iter reads A1/B1 only
    } lds;

    const int tid = threadIdx.x;
    const int lane = tid & 63;
    const int l15 = lane & 15, lq = lane >> 4;
    const int wc  = tid >> 6;
    const int row0 = blockIdx.x * 32;
    const char* Wb = (const char*)Wt;
    const int br = tid >> 2;      // 0..63 (B row within 64-chunk)
    const int bq = tid & 3;

    f32x4 acc[2][4];
    #pragma unroll
    for (int m = 0; m < 2; m++)
        #pragma unroll
        for (int n = 0; n < 4; n++)
            acc[m][n] = (f32x4){0.f, 0.f, 0.f, 0.f};

    // ---- prologue: stage tile 0 into A0/B0
    {
        #pragma unroll
        for (int c = 0; c < 4; c++) {
            uint4 v = *reinterpret_cast<const uint4*>(Wb + (size_t)(c * 64 + br) * 512 + bq * 16);
            *reinterpret_cast<uint4*>(&lds.t.B0[c * 64 + br][bq * 8]) = v;
        }
        if (CAST) {
            const float* Af = (const float*)Ain;
            float4 v = *reinterpret_cast<const float4*>(&Af[(size_t)(row0 + (tid >> 3)) * 256 + (tid & 7) * 4]);
            uint2 w = make_uint2(pk2bf(v.x, v.y), pk2bf(v.z, v.w));
            *reinterpret_cast<uint2*>((ushort*)lds.t.A0 + tid * 4) = w;
        } else if (tid < 128) {
            const char* Ab = (const char*)Ain;
            uint4 v = *reinterpret_cast<const uint4*>(Ab + (size_t)(row0 + (tid >> 2)) * 512 + (tid & 3) * 16);
            *reinterpret_cast<uint4*>((ushort*)lds.t.A0 + tid * 8) = v;
        }
        __syncthreads();
    }

    for (int kt = 0; kt < 8; ++kt) {
        ushort (*Acur)[32] = (kt & 1) ? lds.t.A1 : lds.t.A0;
        ushort (*Bcur)[32] = (kt & 1) ? lds.t.B1 : lds.t.B0;
        // fragments for this tile
        bf16x8 af[2], bfr[4];
        #pragma unroll
        for (int m = 0; m < 2; m++)
            af[m] = *reinterpret_cast<const bf16x8*>(&Acur[m * 16 + l15][lq * 8]);
        #pragma unroll
        for (int n = 0; n < 4; n++)
            bfr[n] = *reinterpret_cast<const bf16x8*>(&Bcur[wc * 64 + n * 16 + l15][lq * 8]);
        // issue next tile's global loads (fly under the MFMAs)
        uint4 rb0, rb1, rb2, rb3, ra; float4 rf;
        if (kt < 7) {
            const size_t ko = (size_t)(kt + 1) * 64;
            rb0 = *reinterpret_cast<const uint4*>(Wb + (size_t)(      br) * 512 + bq * 16 + ko);
            rb1 = *reinterpret_cast<const uint4*>(Wb + (size_t)( 64 + br) * 512 + bq * 16 + ko);
            rb2 = *reinterpret_cast<const uint4*>(Wb + (size_t)(128 + br) * 512 + bq * 16 + ko);
            rb3 = *reinterpret_cast<const uint4*>(Wb + (size_t)(192 + br) * 512 + bq * 16 + ko);
            if (CAST) {
                const float* Af = (const float*)Ain;
                rf = *reinterpret_cast<const float4*>(&Af[(size_t)(row0 + (tid >> 3)) * 256 + (kt + 1) * 32 + (tid & 7) * 4]);
            } else if (tid < 128) {
                const char* Ab = (const char*)Ain;
                ra = *reinterpret_cast<const uint4*>(Ab + (size_t)(row0 + (tid >> 2)) * 512 + (tid & 3) * 16 + ko);
            }
        }
        #pragma unroll
        for (int m = 0; m < 2; m++)
            #pragma unroll
            for (int n = 0; n < 4; n++)
                acc[m][n] = __builtin_amdgcn_mfma_f32_16x16x32_bf16(af[m], bfr[n], acc[m][n], 0, 0, 0);
        if (kt < 7) {
            ushort (*Anx)[32] = (kt & 1) ? lds.t.A0 : lds.t.A1;
            ushort (*Bnx)[32] = (kt & 1) ? lds.t.B0 : lds.t.B1;
            *reinterpret_cast<uint4*>(&Bnx[      br][bq * 8]) = rb0;
            *reinterpret_cast<uint4*>(&Bnx[ 64 + br][bq * 8]) = rb1;
            *reinterpret_cast<uint4*>(&Bnx[128 + br][bq * 8]) = rb2;
            *reinterpret_cast<uint4*>(&Bnx[192 + br][bq * 8]) = rb3;
            if (CAST) {
                uint2 w = make_uint2(pk2bf(rf.x, rf.y), pk2bf(rf.z, rf.w));
                *reinterpret_cast<uint2*>((ushort*)Anx + tid * 4) = w;
            } else if (tid < 128) {
                *reinterpret_cast<uint4*>((ushort*)Anx + tid * 8) = ra;
            }
            __syncthreads();
        }
    }

    // ---- epilogue: repack via per-wave LDS strip (aliases buf0; last iter read buf1)
    const int head = wc;
    const int r  = lane >> 2;               // row within 16-row strip
    const int cq = lane & 3;                // 16-col quarter
    #pragma unroll
    for (int m = 0; m < 2; m++) {
        #pragma unroll
        for (int n = 0; n < 4; n++)
            #pragma unroll
            for (int reg = 0; reg < 4; reg++)
                lds.strip[wc][lq * 4 + reg][n * 16 + l15] = acc[m][n][reg];
        f32x4 c0 = *reinterpret_cast<const f32x4*>(&lds.strip[wc][r][cq * 16]);
        f32x4 c1 = *reinterpret_cast<const f32x4*>(&lds.strip[wc][r][cq * 16 + 4]);
        f32x4 c2 = *reinterpret_cast<const f32x4*>(&lds.strip[wc][r][cq * 16 + 8]);
        f32x4 c3 = *reinterpret_cast<const f32x4*>(&lds.strip[wc][r][cq * 16 + 12]);
        float ps = 0.f, pd = 0.f;
        #pragma unroll
        for (int k4 = 0; k4 < 4; k4++) {
            f32x4 cv = (k4 == 0) ? c0 : (k4 == 1) ? c1 : (k4 == 2) ? c2 : c3;
            #pragma unroll
            for (int j = 0; j < 4; j++) {
                ps = fmaf(cv[j], a_s[head * 64 + cq * 16 + k4 * 4 + j], ps);
                pd = fmaf(cv[j], a_d[head * 64 + cq * 16 + k4 * 4 + j], pd);
            }
        }
        ps += __shfl_xor(ps, 1, 4); ps += __shfl_xor(ps, 2, 4);
        pd += __shfl_xor(pd, 1, 4); pd += __shfl_xor(pd, 2, 4);
        const int row = row0 + m * 16 + r;
        if (cq == 0) {
            asrc[row * 4 + head] = ps;
            adst[row * 4 + head] = pd;
        }
        uint4 o0 = make_uint4(pk2bf(c0[0], c0[1]), pk2bf(c0[2], c0[3]),
                              pk2bf(c1[0], c1[1]), pk2bf(c1[2], c1[3]));
        uint4 o1 = make_uint4(pk2bf(c2[0], c2[1]), pk2bf(c2[2], c2[3]),
                              pk2bf(c3[0], c3[1]), pk2bf(c3[2], c3[3]));
        __hip_bfloat16* Cp = C + (size_t)row * 256 + wc * 64 + cq * 16;
        *reinterpret_cast<uint4*>(Cp) = o0;
        *reinterpret_cast<uint4*>(Cp + 8) = o1;
    }
}

// ---------------- fused edge-softmax + aggregation (max-free, wave-per-head) ----------------

#define ACHUNK 256

__global__ __launch_bounds__(256)
void gat_fused_agg(const __hip_bfloat16* __restrict__ h, const float* __restrict__ asrc,
                   const float* __restrict__ adst, const int* __restrict__ rowptr,
                   const int* __restrict__ csr_src, const float* __restrict__ bias,
                   __hip_bfloat16* __restrict__ out, int do_relu) {
    __shared__ int   s_src[ACHUNK];
    __shared__ float s_w[ACHUNK][5];    // pad 4->5: conflict-free phase-0 writes
    __shared__ float s_acc[8][HC];
    __shared__ float s_sum[4];

    const int n = blockIdx.x;
    const int t = threadIdx.x;
    const int lane = t & 63;
    const int wid = t >> 6;         // wave id == head in phase 0
    const int grp = t >> 5;         // phase-1 group (edge parity)
    const int gl  = t & 31;         // lane in group; channels gl*8..gl*8+7
    const int h3  = gl >> 3;        // head owning those channels
    const int start = rowptr[n];
    const int deg = rowptr[n + 1] - start;
    const float ad = adst[n * 4 + wid];

    float ssum = 0.f;
    float acc[8] = {0.f, 0.f, 0.f, 0.f, 0.f, 0.f, 0.f, 0.f};

    for (int c0 = 0; c0 < deg; c0 += ACHUNK) {
        const int cn = min(ACHUNK, deg - c0);
        if (c0) __syncthreads();
        for (int e = lane; e < cn; e += 64) {
            int src = csr_src[start + c0 + e];
            if (wid == 0) s_src[e] = src;
            float sc = asrc[src * 4 + wid] + ad;
            sc = (sc >= 0.f) ? sc : 0.2f * sc;   // leaky relu 0.2
            float w = __expf(sc);
            s_w[e][wid] = w;
            ssum += w;
        }
        __syncthreads();
        #pragma unroll 2
        for (int e = grp; e < cn; e += 8) {
            float w = s_w[e][h3];
            uint4 v = *reinterpret_cast<const uint4*>(&h[(size_t)s_src[e] * HC + gl * 8]);
            acc[0] = fmaf(w, bflo(v.x), acc[0]);
            acc[1] = fmaf(w, bfhi(v.x), acc[1]);
            acc[2] = fmaf(w, bflo(v.y), acc[2]);
            acc[3] = fmaf(w, bfhi(v.y), acc[3]);
            acc[4] = fmaf(w, bflo(v.z), acc[4]);
            acc[5] = fmaf(w, bfhi(v.z), acc[5]);
            acc[6] = fmaf(w, bflo(v.w), acc[6]);
            acc[7] = fmaf(w, bfhi(v.w), acc[7]);
        }
    }
    #pragma unroll
    for (int off = 1; off < 64; off <<= 1) ssum += __shfl_xor(ssum, off, 64);
    if (lane == 0) s_sum[wid] = ssum;
    *reinterpret_cast<float4*>(&s_acc[grp][gl * 8])     = make_float4(acc[0], acc[1], acc[2], acc[3]);
    *reinterpret_cast<float4*>(&s_acc[grp][gl * 8 + 4]) = make_float4(acc[4], acc[5], acc[6], acc[7]);
    __syncthreads();
    float tot = 0.f;
    #pragma unroll
    for (int g = 0; g < 8; g++) tot += s_acc[g][t];
    float r = tot / s_sum[t >> 6] + bias[t];
    if (do_relu) r = fmaxf(r, 0.f);
    out[(size_t)n * HC + t] = __float2bfloat16(r);
}

// ---------------- fused pool + MLP layer 1 (one block per graph) ----------------

__global__ __launch_bounds__(1024)
void pool_mlp1_kernel(const __hip_bfloat16* __restrict__ h, const int* __restrict__ batch,
                      const float* __restrict__ Wm1, const float* __restrict__ bm1,
                      float* __restrict__ hidden) {
    __shared__ float s_part[4][256];
    __shared__ float row[256];
    const int g = blockIdx.x, t = threadIdx.x;
    int lo = 0, hi = N_NODES;
    while (lo < hi) { int mid = (lo + hi) >> 1; if (batch[mid] < g) lo = mid + 1; else hi = mid; }
    const int start = lo;
    lo = 0; hi = N_NODES;
    while (lo < hi) { int mid = (lo + hi) >> 1; if (batch[mid] < g + 1) lo = mid + 1; else hi = mid; }
    const int end = lo;

    const int sub = t >> 8, ch = t & 255;
    float a = 0.f;
    for (int n = start + sub; n < end; n += 4)
        a += __bfloat162float(h[(size_t)n * HC + ch]);
    s_part[sub][ch] = a;
    __syncthreads();
    if (t < 256) {
        float c = (float)max(end - start, 1);
        row[t] = (s_part[0][t] + s_part[1][t] + s_part[2][t] + s_part[3][t]) / c;
    }
    __syncthreads();
    float acc = bm1[t];
    for (int k = 0; k < 256; k++) acc = fmaf(row[k], Wm1[(size_t)k * NHID + t], acc);
    hidden[(size_t)g * NHID + t] = fmaxf(acc, 0.f);
}

__global__ __launch_bounds__(768)
void mlp2_kernel(const float* __restrict__ hidden, const float* __restrict__ W,
                 const float* __restrict__ b, float* __restrict__ out) {
    __shared__ float row[NHID];
    const int g = blockIdx.x, t = threadIdx.x;
    row[t] = hidden[g * NHID + t];
    if (t < NHID - NOUT) row[NOUT + t] = hidden[g * NHID + NOUT + t];
    __syncthreads();
    float acc = b[t];
    for (int k = 0; k < NHID; k++) acc = fmaf(row[k], W[(size_t)k * NOUT + t], acc);
    out[g * NOUT + t] = acc;
}

// ---------------- launch ----------------

extern "C" void kernel_launch(void* const* d_in, const int* in_sizes, int n_in,
                              void* d_out, int out_size, void* d_ws, size_t ws_size,
                              hipStream_t stream) {
    const float* x  = (const float*)d_in[0];
    const int* ei   = (const int*)d_in[1];
    const int* batch = (const int*)d_in[2];
    const float* W1 = (const float*)d_in[3];
    const float* as1 = (const float*)d_in[4];
    const float* ad1 = (const float*)d_in[5];
    const float* b1 = (const float*)d_in[6];
    const float* W2 = (const float*)d_in[7];
    const float* as2 = (const float*)d_in[8];
    const float* ad2 = (const float*)d_in[9];
    const float* b2 = (const float*)d_in[10];
    const float* W3 = (const float*)d_in[11];
    const float* as3 = (const float*)d_in[12];
    const float* ad3 = (const float*)d_in[13];
    const float* b3 = (const float*)d_in[14];
    const float* Wm1 = (const float*)d_in[15];
    const float* bm1 = (const float*)d_in[16];
    const float* Wm2 = (const float*)d_in[17];
    const float* bm2 = (const float*)d_in[18];
    float* out = (float*)d_out;

    char* base = (char*)d_ws;
    size_t off = 0;
    auto alloc = [&](size_t bytes) { char* p = base + off; off = (off + bytes + 255) & ~(size_t)255; return p; };
    __hip_bfloat16* hA   = (__hip_bfloat16*)alloc((size_t)N_NODES * 256 * 2);
    __hip_bfloat16* hB   = (__hip_bfloat16*)alloc((size_t)N_NODES * 256 * 2);
    __hip_bfloat16* Wt1  = (__hip_bfloat16*)alloc((size_t)256 * 256 * 2);
    __hip_bfloat16* Wt2  = (__hip_bfloat16*)alloc((size_t)256 * 256 * 2);
    __hip_bfloat16* Wt3  = (__hip_bfloat16*)alloc((size_t)256 * 256 * 2);
    float* asrc   = (float*)alloc((size_t)N_NODES * 4 * 4);
    float* adst   = (float*)alloc((size_t)N_NODES * 4 * 4);
    int*   deg    = (int*)alloc((size_t)N_NODES * 4);      // adjacent to cursor:
    int*   cursor = (int*)alloc((size_t)N_NODES * 4);      // single memset covers both
    int*   rowptr = (int*)alloc((size_t)(N_NODES + 1) * 4);
    int*   bsum   = (int*)alloc((size_t)SCAN_NB * 4);
    int*   csrsrc = (int*)alloc((size_t)E_TOT * 4);
    float* hidden = (float*)alloc((size_t)N_GRAPH * NHID * 4);
    (void)ws_size; (void)n_in; (void)in_sizes; (void)out_size;

    hipMemsetAsync(deg, 0, (size_t)N_NODES * 4 * 2, stream);   // deg + cursor

    conv_wt3_kernel<<<dim3(256, 3), 256, 0, stream>>>(W1, W2, W3, Wt1, Wt2, Wt3);

    // CSR (multi-block scan)
    const int eb = (E_TOT + 255) / 256;
    count_deg_kernel<<<eb, 256, 0, stream>>>(ei, deg);
    scan_p1_kernel<<<SCAN_NB, 256, 0, stream>>>(deg, bsum);
    scan_p2_kernel<<<1, 256, 0, stream>>>(bsum);
    scan_p3_kernel<<<SCAN_NB, 256, 0, stream>>>(deg, bsum, rowptr);
    fill_csr_kernel<<<eb, 256, 0, stream>>>(ei, rowptr, cursor, csrsrc);

    const int ggrid = N_NODES / 32;   // 1250, exact

    // layer 1 (A = x, fp32, cast fused into staging)
    gemm_mfma_kernel<1><<<ggrid, 256, 0, stream>>>(x, Wt1, hA, as1, ad1, asrc, adst);
    gat_fused_agg<<<N_NODES, 256, 0, stream>>>(hA, asrc, adst, rowptr, csrsrc, b1, hB, 1);
    // layer 2
    gemm_mfma_kernel<0><<<ggrid, 256, 0, stream>>>(hB, Wt2, hA, as2, ad2, asrc, adst);
    gat_fused_agg<<<N_NODES, 256, 0, stream>>>(hA, asrc, adst, rowptr, csrsrc, b2, hB, 1);
    // layer 3
    gemm_mfma_kernel<0><<<ggrid, 256, 0, stream>>>(hB, Wt3, hA, as3, ad3, asrc, adst);
    gat_fused_agg<<<N_NODES, 256, 0, stream>>>(hA, asrc, adst, rowptr, csrsrc, b3, hB, 0);

    // fused pool+mlp1, then mlp2
    pool_mlp1_kernel<<<N_GRAPH, 1024, 0, stream>>>(hB, batch, Wm1, bm1, hidden);
    mlp2_kernel<<<N_GRAPH, NOUT, 0, stream>>>(hidden, Wm2, bm2, out);
}